// Round 8
// baseline (212.087 us; speedup 1.0000x reference)
//
#include <hip/hip_runtime.h>
#include <math.h>

#define T_TOKENS 16384
#define D_DIM    2048
#define NEXP     256
#define TOPK     8
#define NLIM     4
#define BM       64
#define BK       32
#define KSTEPS   (D_DIM / BK)   // 64
#define NTHREADS 512

typedef __attribute__((ext_vector_type(8))) short bf16x8;   // 8 bf16 (4 VGPRs)
typedef __attribute__((ext_vector_type(4))) float f32x4;    // MFMA acc

typedef __attribute__((address_space(1))) const unsigned short g_ushort;
typedef __attribute__((address_space(3))) unsigned short l_ushort;

// LDS plan (union, 80 KB + hist -> 1 block/CU of 8 waves):
//  A[2][2][4][64][8]  bf16 : x splits, fragment-linear, dbuf   16 KB
//  B[2][2][16][64][8] bf16 : w splits, gll dest, dbuf          64 KB
//  Sc[64][256] f32 : logits->scores for routing (aliases A/B after GEMM)
struct GemmBufs {
  unsigned short A[2][2][4][64][8];   // [buf][split][mfg][lane][j]
  unsigned short B[2][2][16][64][8];  // [buf][split][nfg][lane][j]
};
union SMem {
  GemmBufs g;
  float Sc[BM][NEXP];
};
static_assert(sizeof(SMem) == 81920, "LDS budget");

__device__ __forceinline__ unsigned rtn_hi(float f) {  // RTN-even bf16 in hi16
  unsigned u = __float_as_uint(f);
  return (u + 0x7FFFu + ((u >> 16) & 1u)) & 0xFFFF0000u;
}
__device__ __forceinline__ void split2b(float f, unsigned& h0, unsigned& h1) {
  h0 = rtn_hi(f);
  float r = f - __uint_as_float(h0);
  h1 = rtn_hi(r);
}
// pack 4 consecutive-k floats into split uint2s (lo16 = even k, hi16 = odd k)
__device__ __forceinline__ void pack_split(const float4& v, uint2& p0, uint2& p1) {
  unsigned a0, a1, b0, b1, c0, c1, d0, d1;
  split2b(v.x, a0, a1); split2b(v.y, b0, b1);
  split2b(v.z, c0, c1); split2b(v.w, d0, d1);
  p0.x = (a0 >> 16) | b0;  p0.y = (c0 >> 16) | d0;
  p1.x = (a1 >> 16) | b1;  p1.y = (c1 >> 16) | d1;
}

// ---- pre-pass: w[256][2048] f32 -> 2 bf16 splits in MFMA-fragment order ----
// wf layout (bf16 elems): [ks(64)][split(2)][nfg(16)][lane(64)][j(8)]
// value = split_s( w[ e = nfg*16 + (lane&15) ][ k = ks*32 + (lane>>4)*8 + j ] )
__global__ __launch_bounds__(256) void prep_w(const float* __restrict__ w,
                                              unsigned short* __restrict__ wf) {
  const int g   = blockIdx.x * 256 + threadIdx.x;  // 0..65535
  const int ks  = g >> 10;
  const int rem = g & 1023;
  const int nfg = rem >> 6;
  const int l   = rem & 63;
  const int e   = nfg * 16 + (l & 15);
  const int kb  = ks * 32 + ((l >> 4) << 3);
  const float* src = &w[(size_t)e * D_DIM + kb];
  float f[8];
  *reinterpret_cast<float4*>(&f[0]) = *reinterpret_cast<const float4*>(src);
  *reinterpret_cast<float4*>(&f[4]) = *reinterpret_cast<const float4*>(src + 4);
  union { unsigned u[4]; float4 v; } h[2];
  #pragma unroll
  for (int q = 0; q < 4; ++q) {
    unsigned lo0, lo1, hi0, hi1;
    split2b(f[2 * q],     lo0, lo1);
    split2b(f[2 * q + 1], hi0, hi1);
    h[0].u[q] = (lo0 >> 16) | hi0;
    h[1].u[q] = (lo1 >> 16) | hi1;
  }
  const size_t base = (size_t)ks * 16384 + (size_t)nfg * 512 + (size_t)l * 8;
  *reinterpret_cast<float4*>(wf + base)        = h[0].v;
  *reinterpret_cast<float4*>(wf + base + 8192) = h[1].v;
}

// ---- one K-step of the 2-phase pipeline ----
// stage(t+1): gll B[np] + ds_write A[np] (from xc); load x(t+2) -> xn;
// compute(t) from buf p; counted-vmcnt barrier.
__device__ __forceinline__ void gstep(
    int t, const float* xp, const unsigned short* wf,
    int wid, int lane, int wr, int wc,
    int s_mfg, int s_lane, int s_j,
    float4& xc, float4& xn, SMem& sm, f32x4 (&acc)[2][4]) {
  const int p  = t & 1;
  const int np = p ^ 1;
  const bool more = (t + 1 < KSTEPS);

  // (a) issue async B stage for t+1 (wave-uniform LDS base + lane*16)
  if (more) {
    #pragma unroll
    for (int i = 0; i < 4; ++i) {
      const int c = wid * 4 + i, s = c >> 4, nfg = c & 15;
      __builtin_amdgcn_global_load_lds(
          (g_ushort*)(wf + (size_t)(t + 1) * 16384 + s * 8192 + nfg * 512 +
                      lane * 8),
          (l_ushort*)&sm.g.B[np][s][nfg][0][0], 16, 0, 0);
    }
  }
  // (b) issue x load for t+2 (private; allowed to cross the barrier)
  if (t + 2 < KSTEPS)
    xn = *reinterpret_cast<const float4*>(xp + (t + 2) * BK);
  __builtin_amdgcn_sched_barrier(0);

  // (c) compute step t from buf p
  {
    bf16x8 af[2][2];
    #pragma unroll
    for (int mf = 0; mf < 2; ++mf)
      #pragma unroll
      for (int s = 0; s < 2; ++s)
        af[mf][s] = *reinterpret_cast<const bf16x8*>(
            &sm.g.A[p][s][wr * 2 + mf][lane][0]);
    #pragma unroll
    for (int nf = 0; nf < 4; ++nf) {
      bf16x8 b0 = *reinterpret_cast<const bf16x8*>(
          &sm.g.B[p][0][wc * 4 + nf][lane][0]);
      bf16x8 b1 = *reinterpret_cast<const bf16x8*>(
          &sm.g.B[p][1][wc * 4 + nf][lane][0]);
      #pragma unroll
      for (int mf = 0; mf < 2; ++mf) {
        f32x4 c = acc[mf][nf];
        c = __builtin_amdgcn_mfma_f32_16x16x32_bf16(af[mf][1], b0, c, 0, 0, 0);
        c = __builtin_amdgcn_mfma_f32_16x16x32_bf16(af[mf][0], b1, c, 0, 0, 0);
        c = __builtin_amdgcn_mfma_f32_16x16x32_bf16(af[mf][0], b0, c, 0, 0, 0);
        acc[mf][nf] = c;
      }
    }
  }
  __builtin_amdgcn_sched_barrier(0);

  // (d) split x(t+1) -> A[np]
  if (more) {
    uint2 p0, p1;
    pack_split(xc, p0, p1);
    *reinterpret_cast<uint2*>(&sm.g.A[np][0][s_mfg][s_lane][s_j]) = p0;
    *reinterpret_cast<uint2*>(&sm.g.A[np][1][s_mfg][s_lane][s_j]) = p1;
  }

  // (e) counted-vmcnt barrier: retire glls (had a full step), keep xn flying
  asm volatile("s_waitcnt vmcnt(1) lgkmcnt(0)" ::: "memory");
  __builtin_amdgcn_sched_barrier(0);
  __builtin_amdgcn_s_barrier();
  __builtin_amdgcn_sched_barrier(0);
}

// ---- fused GEMM (bf16x2 MFMA, LDS 2-phase pipeline) + routing ----
__global__ __launch_bounds__(NTHREADS, 2) void gate_kernel(
    const float* __restrict__ x,
    const unsigned short* __restrict__ wf,
    const float* __restrict__ bias,
    float* __restrict__ out_w,
    float* __restrict__ out_idx,
    float* __restrict__ out_load) {

  __shared__ SMem sm;
  __shared__ int hist[NEXP];

  const int tid  = threadIdx.x;
  const int row0 = blockIdx.x * BM;
  const int lane = tid & 63;
  const int wid  = tid >> 6;   // 0..7
  const int wr   = wid >> 2;   // wave row: 32 tokens
  const int wc   = wid & 3;    // wave col: 64 experts

  for (int i = tid; i < NEXP; i += NTHREADS) hist[i] = 0;

  // A staging map: thread -> (token row, 4 consecutive k)
  const int srow = tid >> 3;            // 0..63
  const int kq   = (tid & 7) * 4;       // 0..28
  const float* xp = &x[(size_t)(row0 + srow) * D_DIM + kq];
  const int s_mfg  = srow >> 4;
  const int s_lane = ((kq >> 3) << 4) | (srow & 15);
  const int s_j    = kq & 7;            // 0 or 4

  f32x4 acc[2][4];
  #pragma unroll
  for (int i = 0; i < 2; ++i)
    #pragma unroll
    for (int j = 0; j < 4; ++j) acc[i][j] = (f32x4)(0.0f);

  float4 xA, xB;

  // ---- prologue: stage step 0 into buf 0, prefetch x(1)
  #pragma unroll
  for (int i = 0; i < 4; ++i) {
    const int c = wid * 4 + i, s = c >> 4, nfg = c & 15;
    __builtin_amdgcn_global_load_lds(
        (g_ushort*)(wf + (size_t)s * 8192 + nfg * 512 + lane * 8),
        (l_ushort*)&sm.g.B[0][s][nfg][0][0], 16, 0, 0);
  }
  xA = *reinterpret_cast<const float4*>(xp);
  xB = *reinterpret_cast<const float4*>(xp + BK);
  {
    uint2 p0, p1;
    pack_split(xA, p0, p1);   // waits xA; xB stays in flight
    *reinterpret_cast<uint2*>(&sm.g.A[0][0][s_mfg][s_lane][s_j]) = p0;
    *reinterpret_cast<uint2*>(&sm.g.A[0][1][s_mfg][s_lane][s_j]) = p1;
  }
  asm volatile("s_waitcnt vmcnt(1) lgkmcnt(0)" ::: "memory");
  __builtin_amdgcn_sched_barrier(0);
  __builtin_amdgcn_s_barrier();
  __builtin_amdgcn_sched_barrier(0);

  // ---- main loop: unroll by 2 so the x-ring uses static register names
  for (int t = 0; t < KSTEPS; t += 2) {
    gstep(t,     xp, wf, wid, lane, wr, wc, s_mfg, s_lane, s_j, xB, xA, sm, acc);
    gstep(t + 1, xp, wf, wid, lane, wr, wc, s_mfg, s_lane, s_j, xA, xB, sm, acc);
  }

  // ---- epilogue: logits -> Sc (C/D layout: col=lane&15, row=(lane>>4)*4+r)
  #pragma unroll
  for (int mf = 0; mf < 2; ++mf)
    #pragma unroll
    for (int nf = 0; nf < 4; ++nf)
      #pragma unroll
      for (int r = 0; r < 4; ++r) {
        const int row = wr * 32 + mf * 16 + ((lane >> 4) << 2) + r;
        const int col = wc * 64 + nf * 16 + (lane & 15);
        sm.Sc[row][col] = acc[mf][nf][r];
      }
  __syncthreads();

  // ---- routing: one wave per token, lane holds experts 4l..4l+3
  const float4 bsl = *reinterpret_cast<const float4*>(&bias[lane * 4]);
  const int g = lane >> 3;   // group of this lane's experts

  for (int m = wid; m < BM; m += 8) {
    float v[4];
    *reinterpret_cast<float4*>(v) =
        *reinterpret_cast<const float4*>(&sm.Sc[m][lane * 4]);

    // softmax (match jax: subtract row max, exp, divide by sum)
    float mx = fmaxf(fmaxf(v[0], v[1]), fmaxf(v[2], v[3]));
    #pragma unroll
    for (int s = 1; s < 64; s <<= 1) mx = fmaxf(mx, __shfl_xor(mx, s));
    float ex[4], sum = 0.f;
    #pragma unroll
    for (int j = 0; j < 4; ++j) { ex[j] = expf(v[j] - mx); sum += ex[j]; }
    #pragma unroll
    for (int s = 1; s < 64; s <<= 1) sum += __shfl_xor(sum, s);
    float sc[4], sel[4];
    sc[0] = ex[0] / sum; sc[1] = ex[1] / sum;
    sc[2] = ex[2] / sum; sc[3] = ex[3] / sum;
    sel[0] = sc[0] + bsl.x; sel[1] = sc[1] + bsl.y;
    sel[2] = sc[2] + bsl.z; sel[3] = sc[3] + bsl.w;

    // keep original scores for the gather
    *reinterpret_cast<float4*>(&sm.Sc[m][lane * 4]) =
        make_float4(sc[0], sc[1], sc[2], sc[3]);

    // group max (groups of 32 experts = 8 lanes)
    float gv = fmaxf(fmaxf(sel[0], sel[1]), fmaxf(sel[2], sel[3]));
    gv = fmaxf(gv, __shfl_xor(gv, 1));
    gv = fmaxf(gv, __shfl_xor(gv, 2));
    gv = fmaxf(gv, __shfl_xor(gv, 4));

    // top-4 groups, tie -> lower group index (jax.lax.top_k stability)
    unsigned gmask = 0;
    float gcur = gv;
    #pragma unroll
    for (int it = 0; it < NLIM; ++it) {
      float bv2 = gcur; int bi = g;
      #pragma unroll
      for (int s = 1; s < 64; s <<= 1) {
        float ov = __shfl_xor(bv2, s);
        int   oi = __shfl_xor(bi, s);
        if (ov > bv2 || (ov == bv2 && oi < bi)) { bv2 = ov; bi = oi; }
      }
      gmask |= 1u << bi;
      if (g == bi) gcur = -INFINITY;
    }
    if (!((gmask >> g) & 1u)) {
      sel[0] = sel[1] = sel[2] = sel[3] = -INFINITY;
    }

    // top-8 experts, tie -> lower expert index
    const int gtok = row0 + m;
    #pragma unroll
    for (int it = 0; it < TOPK; ++it) {
      float bv2 = sel[0]; int bi = lane * 4;
      #pragma unroll
      for (int j = 1; j < 4; ++j)
        if (sel[j] > bv2) { bv2 = sel[j]; bi = lane * 4 + j; }
      #pragma unroll
      for (int s = 1; s < 64; s <<= 1) {
        float ov = __shfl_xor(bv2, s);
        int   oi = __shfl_xor(bi, s);
        if (ov > bv2 || (ov == bv2 && oi < bi)) { bv2 = ov; bi = oi; }
      }
      if (lane == 0) {
        out_w[(size_t)gtok * TOPK + it]   = sm.Sc[m][bi] * 2.5f;
        out_idx[(size_t)gtok * TOPK + it] = (float)bi;
        atomicAdd(&hist[bi], 1);
      }
      if ((bi >> 2) == lane) sel[bi & 3] = -INFINITY;
    }
  }

  __syncthreads();
  for (int b = tid; b < NEXP; b += NTHREADS)
    if (hist[b]) atomicAdd(&out_load[b], (float)hist[b]);
}

extern "C" void kernel_launch(void* const* d_in, const int* in_sizes, int n_in,
                              void* d_out, int out_size, void* d_ws, size_t ws_size,
                              hipStream_t stream) {
  const float* x    = (const float*)d_in[0];
  const float* w    = (const float*)d_in[1];
  const float* bias = (const float*)d_in[2];
  float* out_w    = (float*)d_out;
  float* out_idx  = out_w + (size_t)T_TOKENS * TOPK;
  float* out_load = out_idx + (size_t)T_TOKENS * TOPK;
  unsigned short* wfrag = (unsigned short*)d_ws;   // 2 MB fragment-ordered w splits

  hipMemsetAsync(out_load, 0, NEXP * sizeof(float), stream);
  prep_w<<<256, 256, 0, stream>>>(w, wfrag);
  gate_kernel<<<T_TOKENS / BM, NTHREADS, 0, stream>>>(
      x, wfrag, bias, out_w, out_idx, out_load);
}

// Round 9
// 129.633 us; speedup vs baseline: 1.6361x; 1.6361x over previous
//
#include <hip/hip_runtime.h>
#include <hip/hip_fp16.h>
#include <math.h>

#define T_TOKENS 16384
#define D_DIM    2048
#define NEXP     256
#define TOPK     8
#define NLIM     4
#define BM       32
#define BK       32
#define KSTEPS   (D_DIM / BK)   // 64
#define NTHREADS 512

typedef __attribute__((ext_vector_type(8))) _Float16 f16x8;  // 4 VGPRs
typedef __attribute__((ext_vector_type(4))) float f32x4;     // MFMA acc

typedef __attribute__((address_space(1))) const unsigned short g_ushort;
typedef __attribute__((address_space(3))) unsigned short l_ushort;

// LDS (union, ~37 KB -> 2 blocks/CU with grid 512 = all 256 CUs, 4 waves/SIMD):
//  A[2][2][64][8]  fp16 : x tile, fragment-linear, dbuf    4 KB
//  B[2][16][64][8] fp16 : w tile, gll dest, dbuf          32 KB
//  Sc[32][256] f32 : logits->scores for routing (aliases A/B after GEMM)
struct GemmBufs {
  unsigned short A[2][2][64][8];   // [buf][mfg][lane][j]
  unsigned short B[2][16][64][8];  // [buf][nfg][lane][j]
};
union SMem {
  GemmBufs g;
  float Sc[BM][NEXP];
};
static_assert(sizeof(SMem) == 36864, "LDS budget");

// ---- pre-pass: w[256][2048] f32 -> fp16 in MFMA-fragment order ----
// wf layout (fp16 elems): [ks(64)][nfg(16)][lane(64)][j(8)]
// value = (half) w[ e = nfg*16 + (lane&15) ][ k = ks*32 + (lane>>4)*8 + j ]
__global__ __launch_bounds__(256) void prep_w(const float* __restrict__ w,
                                              unsigned short* __restrict__ wf) {
  const int g   = blockIdx.x * 256 + threadIdx.x;  // 0..65535
  const int ks  = g >> 10;
  const int rem = g & 1023;
  const int nfg = rem >> 6;
  const int l   = rem & 63;
  const int e   = nfg * 16 + (l & 15);
  const int kb  = ks * 32 + ((l >> 4) << 3);
  const float* src = &w[(size_t)e * D_DIM + kb];
  float f[8];
  *reinterpret_cast<float4*>(&f[0]) = *reinterpret_cast<const float4*>(src);
  *reinterpret_cast<float4*>(&f[4]) = *reinterpret_cast<const float4*>(src + 4);
  union { unsigned short s[8]; float4 v; } h;
  #pragma unroll
  for (int j = 0; j < 8; ++j) h.s[j] = __half_as_ushort(__float2half(f[j]));
  *reinterpret_cast<float4*>(wf + (size_t)ks * 8192 + nfg * 512 + l * 8) = h.v;
}

__device__ __forceinline__ unsigned cvt2(const float2& v) {
  return (unsigned)__half_as_ushort(__float2half(v.x)) |
         ((unsigned)__half_as_ushort(__float2half(v.y)) << 16);
}

// ---- one main-loop K-step (always has 1 x-load in flight at the barrier) --
__device__ __forceinline__ void gstep(
    int t, const float* xp, const unsigned short* wf,
    int wid, int lane,
    int a_mfg, int a_lane, int a_q,
    float2& xc, float2& xn, SMem& sm, f32x4 (&acc)[2][2]) {
  const int p = t & 1, np = p ^ 1;

  // (a) async-stage B(t+1): 16 chunks of 1 KB, 2 per wave (wave-uniform dest)
  #pragma unroll
  for (int i = 0; i < 2; ++i) {
    const int c = wid * 2 + i;
    __builtin_amdgcn_global_load_lds(
        (g_ushort*)(wf + (size_t)(t + 1) * 8192 + c * 512 + lane * 8),
        (l_ushort*)&sm.g.B[np][c][0][0], 16, 0, 0);
  }
  // (b) x load for t+2 (private; crosses the barrier via counted vmcnt)
  xn = *reinterpret_cast<const float2*>(xp + (t + 2) * BK);
  __builtin_amdgcn_sched_barrier(0);

  // (c) compute step t from buf p
  {
    f16x8 a0 = *reinterpret_cast<const f16x8*>(&sm.g.A[p][0][lane][0]);
    f16x8 a1 = *reinterpret_cast<const f16x8*>(&sm.g.A[p][1][lane][0]);
    #pragma unroll
    for (int nf = 0; nf < 2; ++nf) {
      f16x8 b = *reinterpret_cast<const f16x8*>(
          &sm.g.B[p][wid * 2 + nf][lane][0]);
      acc[0][nf] = __builtin_amdgcn_mfma_f32_16x16x32_f16(a0, b, acc[0][nf], 0, 0, 0);
      acc[1][nf] = __builtin_amdgcn_mfma_f32_16x16x32_f16(a1, b, acc[1][nf], 0, 0, 0);
    }
  }
  __builtin_amdgcn_sched_barrier(0);

  // (d) convert x(t+1) -> A[np] (consecutive 4B addrs: conflict-free)
  *reinterpret_cast<unsigned*>(&sm.g.A[np][a_mfg][a_lane][a_q * 2]) = cvt2(xc);

  // (e) counted barrier: drain the 2 glls (had the whole step), keep xn flying
  asm volatile("s_waitcnt vmcnt(1) lgkmcnt(0)" ::: "memory");
  __builtin_amdgcn_sched_barrier(0);
  __builtin_amdgcn_s_barrier();
  __builtin_amdgcn_sched_barrier(0);
}

// ---- fused GEMM (fp16 MFMA, LDS 2-phase) + softmax + grouped top-k ----
__global__ __launch_bounds__(NTHREADS, 4) void gate_kernel(
    const float* __restrict__ x,
    const unsigned short* __restrict__ wf,
    const float* __restrict__ bias,
    float* __restrict__ out_w,
    float* __restrict__ out_idx,
    float* __restrict__ out_load) {

  __shared__ SMem sm;
  __shared__ int hist[NEXP];

  const int tid  = threadIdx.x;
  const int row0 = blockIdx.x * BM;
  const int lane = tid & 63;
  const int wid  = tid >> 6;   // 0..7 ; wave owns experts wid*32..wid*32+31

  for (int i = tid; i < NEXP; i += NTHREADS) hist[i] = 0;

  // A staging map: thread -> (mfg, lane, quarter): 2 fp16 = 4 B each
  const int a_mfg  = tid >> 8;           // 0..1
  const int a_lane = (tid >> 2) & 63;    // 0..63
  const int a_q    = tid & 3;            // 0..3
  const int arow   = a_mfg * 16 + (a_lane & 15);
  const int akoff  = ((a_lane >> 4) << 3) + a_q * 2;
  const float* xp  = &x[(size_t)(row0 + arow) * D_DIM + akoff];

  f32x4 acc[2][2];
  #pragma unroll
  for (int i = 0; i < 2; ++i)
    #pragma unroll
    for (int j = 0; j < 2; ++j) acc[i][j] = (f32x4)(0.0f);

  float2 xA, xB;

  // ---- prologue: x(0) first (oldest), then stage-0 glls, then x(1)
  float2 x0 = *reinterpret_cast<const float2*>(xp);
  #pragma unroll
  for (int i = 0; i < 2; ++i) {
    const int c = wid * 2 + i;
    __builtin_amdgcn_global_load_lds(
        (g_ushort*)(wf + c * 512 + lane * 8),
        (l_ushort*)&sm.g.B[0][c][0][0], 16, 0, 0);
  }
  xA = *reinterpret_cast<const float2*>(xp + BK);
  *reinterpret_cast<unsigned*>(&sm.g.A[0][a_mfg][a_lane][a_q * 2]) = cvt2(x0);
  asm volatile("s_waitcnt vmcnt(1) lgkmcnt(0)" ::: "memory");
  __builtin_amdgcn_sched_barrier(0);
  __builtin_amdgcn_s_barrier();
  __builtin_amdgcn_sched_barrier(0);

  // ---- main loop t = 0..61 (every step issues x(t+2): vmcnt(1) exact)
  for (int t = 0; t < KSTEPS - 2; t += 2) {
    gstep(t,     xp, wf, wid, lane, a_mfg, a_lane, a_q, xA, xB, sm, acc);
    gstep(t + 1, xp, wf, wid, lane, a_mfg, a_lane, a_q, xB, xA, sm, acc);
  }

  // ---- t = 62: stage t=63, compute buf0, write A[1] <- x(63) (in xA)
  {
    #pragma unroll
    for (int i = 0; i < 2; ++i) {
      const int c = wid * 2 + i;
      __builtin_amdgcn_global_load_lds(
          (g_ushort*)(wf + (size_t)63 * 8192 + c * 512 + lane * 8),
          (l_ushort*)&sm.g.B[1][c][0][0], 16, 0, 0);
    }
    __builtin_amdgcn_sched_barrier(0);
    f16x8 a0 = *reinterpret_cast<const f16x8*>(&sm.g.A[0][0][lane][0]);
    f16x8 a1 = *reinterpret_cast<const f16x8*>(&sm.g.A[0][1][lane][0]);
    #pragma unroll
    for (int nf = 0; nf < 2; ++nf) {
      f16x8 b = *reinterpret_cast<const f16x8*>(&sm.g.B[0][wid * 2 + nf][lane][0]);
      acc[0][nf] = __builtin_amdgcn_mfma_f32_16x16x32_f16(a0, b, acc[0][nf], 0, 0, 0);
      acc[1][nf] = __builtin_amdgcn_mfma_f32_16x16x32_f16(a1, b, acc[1][nf], 0, 0, 0);
    }
    *reinterpret_cast<unsigned*>(&sm.g.A[1][a_mfg][a_lane][a_q * 2]) = cvt2(xA);
    asm volatile("s_waitcnt vmcnt(0) lgkmcnt(0)" ::: "memory");
    __builtin_amdgcn_sched_barrier(0);
    __builtin_amdgcn_s_barrier();
    __builtin_amdgcn_sched_barrier(0);
  }
  // ---- t = 63: compute buf1
  {
    f16x8 a0 = *reinterpret_cast<const f16x8*>(&sm.g.A[1][0][lane][0]);
    f16x8 a1 = *reinterpret_cast<const f16x8*>(&sm.g.A[1][1][lane][0]);
    #pragma unroll
    for (int nf = 0; nf < 2; ++nf) {
      f16x8 b = *reinterpret_cast<const f16x8*>(&sm.g.B[1][wid * 2 + nf][lane][0]);
      acc[0][nf] = __builtin_amdgcn_mfma_f32_16x16x32_f16(a0, b, acc[0][nf], 0, 0, 0);
      acc[1][nf] = __builtin_amdgcn_mfma_f32_16x16x32_f16(a1, b, acc[1][nf], 0, 0, 0);
    }
  }
  __syncthreads();   // all LDS reads done; safe to alias Sc over A/B

  // ---- epilogue: logits -> Sc (C/D layout: col=lane&15, row=(lane>>4)*4+r)
  #pragma unroll
  for (int mf = 0; mf < 2; ++mf)
    #pragma unroll
    for (int nf = 0; nf < 2; ++nf)
      #pragma unroll
      for (int r = 0; r < 4; ++r) {
        const int row = mf * 16 + ((lane >> 4) << 2) + r;
        const int col = wid * 32 + nf * 16 + (lane & 15);
        sm.Sc[row][col] = acc[mf][nf][r];
      }
  __syncthreads();

  // ---- routing: one wave per token, lane holds experts 4l..4l+3
  const float4 bsl = *reinterpret_cast<const float4*>(&bias[lane * 4]);
  const int g = lane >> 3;   // group of this lane's experts

  for (int m = wid; m < BM; m += 8) {
    float v[4];
    *reinterpret_cast<float4*>(v) =
        *reinterpret_cast<const float4*>(&sm.Sc[m][lane * 4]);

    // softmax (match jax: subtract row max, exp, divide by sum)
    float mx = fmaxf(fmaxf(v[0], v[1]), fmaxf(v[2], v[3]));
    #pragma unroll
    for (int s = 1; s < 64; s <<= 1) mx = fmaxf(mx, __shfl_xor(mx, s));
    float ex[4], sum = 0.f;
    #pragma unroll
    for (int j = 0; j < 4; ++j) { ex[j] = expf(v[j] - mx); sum += ex[j]; }
    #pragma unroll
    for (int s = 1; s < 64; s <<= 1) sum += __shfl_xor(sum, s);
    float sc[4], sel[4];
    sc[0] = ex[0] / sum; sc[1] = ex[1] / sum;
    sc[2] = ex[2] / sum; sc[3] = ex[3] / sum;
    sel[0] = sc[0] + bsl.x; sel[1] = sc[1] + bsl.y;
    sel[2] = sc[2] + bsl.z; sel[3] = sc[3] + bsl.w;

    // keep original scores for the gather
    *reinterpret_cast<float4*>(&sm.Sc[m][lane * 4]) =
        make_float4(sc[0], sc[1], sc[2], sc[3]);

    // group max (groups of 32 experts = 8 lanes)
    float gv = fmaxf(fmaxf(sel[0], sel[1]), fmaxf(sel[2], sel[3]));
    gv = fmaxf(gv, __shfl_xor(gv, 1));
    gv = fmaxf(gv, __shfl_xor(gv, 2));
    gv = fmaxf(gv, __shfl_xor(gv, 4));

    // top-4 groups, tie -> lower group index (jax.lax.top_k stability)
    unsigned gmask = 0;
    float gcur = gv;
    #pragma unroll
    for (int it = 0; it < NLIM; ++it) {
      float bv2 = gcur; int bi = g;
      #pragma unroll
      for (int s = 1; s < 64; s <<= 1) {
        float ov = __shfl_xor(bv2, s);
        int   oi = __shfl_xor(bi, s);
        if (ov > bv2 || (ov == bv2 && oi < bi)) { bv2 = ov; bi = oi; }
      }
      gmask |= 1u << bi;
      if (g == bi) gcur = -INFINITY;
    }
    if (!((gmask >> g) & 1u)) {
      sel[0] = sel[1] = sel[2] = sel[3] = -INFINITY;
    }

    // top-8 experts, tie -> lower expert index
    const int gtok = row0 + m;
    #pragma unroll
    for (int it = 0; it < TOPK; ++it) {
      float bv2 = sel[0]; int bi = lane * 4;
      #pragma unroll
      for (int j = 1; j < 4; ++j)
        if (sel[j] > bv2) { bv2 = sel[j]; bi = lane * 4 + j; }
      #pragma unroll
      for (int s = 1; s < 64; s <<= 1) {
        float ov = __shfl_xor(bv2, s);
        int   oi = __shfl_xor(bi, s);
        if (ov > bv2 || (ov == bv2 && oi < bi)) { bv2 = ov; bi = oi; }
      }
      if (lane == 0) {
        out_w[(size_t)gtok * TOPK + it]   = sm.Sc[m][bi] * 2.5f;
        out_idx[(size_t)gtok * TOPK + it] = (float)bi;
        atomicAdd(&hist[bi], 1);
      }
      if ((bi >> 2) == lane) sel[bi & 3] = -INFINITY;
    }
  }

  __syncthreads();
  for (int b = tid; b < NEXP; b += NTHREADS)
    if (hist[b]) atomicAdd(&out_load[b], (float)hist[b]);
}

extern "C" void kernel_launch(void* const* d_in, const int* in_sizes, int n_in,
                              void* d_out, int out_size, void* d_ws, size_t ws_size,
                              hipStream_t stream) {
  const float* x    = (const float*)d_in[0];
  const float* w    = (const float*)d_in[1];
  const float* bias = (const float*)d_in[2];
  float* out_w    = (float*)d_out;
  float* out_idx  = out_w + (size_t)T_TOKENS * TOPK;
  float* out_load = out_idx + (size_t)T_TOKENS * TOPK;
  unsigned short* wfrag = (unsigned short*)d_ws;   // 1 MB fragment-ordered fp16 w

  hipMemsetAsync(out_load, 0, NEXP * sizeof(float), stream);
  prep_w<<<256, 256, 0, stream>>>(w, wfrag);
  gate_kernel<<<T_TOKENS / BM, NTHREADS, 0, stream>>>(
      x, wfrag, bias, out_w, out_idx, out_load);
}

// Round 10
// 128.921 us; speedup vs baseline: 1.6451x; 1.0055x over previous
//
#include <hip/hip_runtime.h>
#include <hip/hip_fp16.h>
#include <math.h>

#define T_TOKENS 16384
#define D_DIM    2048
#define NEXP     256
#define TOPK     8
#define NLIM     4
#define BM       32
#define BK       32
#define KSTEPS   (D_DIM / BK)   // 64
#define NTHREADS 512

typedef __attribute__((ext_vector_type(8))) _Float16 f16x8;  // 4 VGPRs
typedef __attribute__((ext_vector_type(4))) float f32x4;     // MFMA acc

typedef __attribute__((address_space(1))) const unsigned short g_ushort;
typedef __attribute__((address_space(3))) unsigned short l_ushort;

// LDS (~53 KB union + 1 KB hist -> 2 blocks/CU, 16 waves/CU):
//  A[2][2][64][8]  fp16 : x tile dbuf (the ONLY cross-wave data)   4 KB
//  B[3][16][64][8] fp16 : w tile 3-ring, WAVE-PRIVATE chunks      48 KB
//  Sc[32][260] f32 : logits->scores (aliases A/B after GEMM)
struct GemmBufs {
  unsigned short A[2][2][64][8];   // [buf][mfg][lane][j]
  unsigned short B[3][16][64][8];  // [ring][nfg][lane][j]
};
union SMem {
  GemmBufs g;
  float Sc[BM][260];
};
static_assert(sizeof(SMem) == 53248, "LDS budget");

// ---- pre-pass: w[256][2048] f32 -> fp16 in MFMA-fragment order ----
// wf layout (fp16 elems): [ks(64)][nfg(16)][lane(64)][j(8)]
// value = (half) w[ e = nfg*16 + (lane&15) ][ k = ks*32 + (lane>>4)*8 + j ]
__global__ __launch_bounds__(256) void prep_w(const float* __restrict__ w,
                                              unsigned short* __restrict__ wf) {
  const int g   = blockIdx.x * 256 + threadIdx.x;  // 0..65535
  const int ks  = g >> 10;
  const int rem = g & 1023;
  const int nfg = rem >> 6;
  const int l   = rem & 63;
  const int e   = nfg * 16 + (l & 15);
  const int kb  = ks * 32 + ((l >> 4) << 3);
  const float* src = &w[(size_t)e * D_DIM + kb];
  float f[8];
  *reinterpret_cast<float4*>(&f[0]) = *reinterpret_cast<const float4*>(src);
  *reinterpret_cast<float4*>(&f[4]) = *reinterpret_cast<const float4*>(src + 4);
  union { unsigned short s[8]; float4 v; } h;
  #pragma unroll
  for (int j = 0; j < 8; ++j) h.s[j] = __half_as_ushort(__float2half(f[j]));
  *reinterpret_cast<float4*>(wf + (size_t)ks * 8192 + nfg * 512 + l * 8) = h.v;
}

__device__ __forceinline__ unsigned cvt2(const float2& v) {
  return (unsigned)__half_as_ushort(__float2half(v.x)) |
         ((unsigned)__half_as_ushort(__float2half(v.y)) << 16);
}

__device__ __forceinline__ void mfma4(const SMem& sm, int t, int wid, int lane,
                                      f32x4 (&acc)[2][2]) {
  const int br = t % 3;
  f16x8 a0 = *reinterpret_cast<const f16x8*>(&sm.g.A[t & 1][0][lane][0]);
  f16x8 a1 = *reinterpret_cast<const f16x8*>(&sm.g.A[t & 1][1][lane][0]);
  f16x8 b0 = *reinterpret_cast<const f16x8*>(&sm.g.B[br][wid * 2 + 0][lane][0]);
  f16x8 b1 = *reinterpret_cast<const f16x8*>(&sm.g.B[br][wid * 2 + 1][lane][0]);
  acc[0][0] = __builtin_amdgcn_mfma_f32_16x16x32_f16(a0, b0, acc[0][0], 0, 0, 0);
  acc[1][0] = __builtin_amdgcn_mfma_f32_16x16x32_f16(a1, b0, acc[1][0], 0, 0, 0);
  acc[0][1] = __builtin_amdgcn_mfma_f32_16x16x32_f16(a0, b1, acc[0][1], 0, 0, 0);
  acc[1][1] = __builtin_amdgcn_mfma_f32_16x16x32_f16(a1, b1, acc[1][1], 0, 0, 0);
}

// ---- one main-loop K-step ----
// issue x(t+2), gll B(t+2); wave-local vmcnt(6) retires own gll(t);
// compute t; cvt x(t+1)->A[(t+1)&1]; barrier waits LDS only (VMEM keeps flying)
__device__ __forceinline__ void gstep(
    int t, const float* xp, const unsigned short* wf,
    int wid, int lane, int a_mfg, int a_lane, int a_q,
    float2& xc /*x(t+1)*/, float2& xn /*fills x(t+2)*/,
    SMem& sm, f32x4 (&acc)[2][2]) {
  // (1) x(t+2) first: max flight, oldest of this step's issues
  xn = *reinterpret_cast<const float2*>(xp + (t + 2) * BK);
  __builtin_amdgcn_sched_barrier(0);
  // (2) B(t+2) -> ring (t+2)%3 (wave-private chunks: no barrier needed for B)
  const int bw = (t + 2) % 3;
  #pragma unroll
  for (int i = 0; i < 2; ++i) {
    const int c = wid * 2 + i;
    __builtin_amdgcn_global_load_lds(
        (g_ushort*)(wf + (size_t)(t + 2) * 8192 + c * 512 + lane * 8),
        (l_ushort*)&sm.g.B[bw][c][0][0], 16, 0, 0);
  }
  __builtin_amdgcn_sched_barrier(0);
  // (3) own gll(t) landed (6 newer VMEM ops outstanding: x(t+1), gll(t+1)x2,
  //     x(t+2), gll(t+2)x2). Compiler cannot see the gll->ds_read dep.
  asm volatile("s_waitcnt vmcnt(6)" ::: "memory");
  __builtin_amdgcn_sched_barrier(0);
  // (4) compute step t
  mfma4(sm, t, wid, lane, acc);
  // (5) x(t+1) -> A[(t+1)&1] (compiler inserts the x(t+1) reg-dep wait here)
  *reinterpret_cast<unsigned*>(
      &sm.g.A[(t + 1) & 1][a_mfg][a_lane][a_q * 2]) = cvt2(xc);
  // (6) A-only barrier: LDS drained, VMEM stays in flight
  asm volatile("s_waitcnt lgkmcnt(0)" ::: "memory");
  __builtin_amdgcn_sched_barrier(0);
  __builtin_amdgcn_s_barrier();
  __builtin_amdgcn_sched_barrier(0);
}

// ---- fused GEMM (fp16 MFMA) + softmax + group-limited top-k routing ----
__global__ __launch_bounds__(NTHREADS, 4) void gate_kernel(
    const float* __restrict__ x,
    const unsigned short* __restrict__ wf,
    const float* __restrict__ bias,
    float* __restrict__ out_w,
    float* __restrict__ out_idx,
    float* __restrict__ out_load) {

  __shared__ SMem sm;
  __shared__ int hist[NEXP];

  const int tid  = threadIdx.x;
  const int row0 = blockIdx.x * BM;
  const int lane = tid & 63;
  const int wid  = tid >> 6;   // 0..7 ; wave owns experts wid*32..wid*32+31

  for (int i = tid; i < NEXP; i += NTHREADS) hist[i] = 0;

  // A staging map: thread -> (mfg, lane, quarter): 2 fp16 = 4 B each
  const int a_mfg  = tid >> 8;           // 0..1
  const int a_lane = (tid >> 2) & 63;    // 0..63
  const int a_q    = tid & 3;            // 0..3
  const int arow   = a_mfg * 16 + (a_lane & 15);
  const int akoff  = ((a_lane >> 4) << 3) + a_q * 2;
  const float* xp  = &x[(size_t)(row0 + arow) * D_DIM + akoff];

  f32x4 acc[2][2];
  #pragma unroll
  for (int i = 0; i < 2; ++i)
    #pragma unroll
    for (int j = 0; j < 2; ++j) acc[i][j] = (f32x4)(0.0f);

  // ---- prologue: x(0), x(1); gll B(0)->ring0, B(1)->ring1; A(0) staged
  float2 x0 = *reinterpret_cast<const float2*>(xp);
  float2 xA = *reinterpret_cast<const float2*>(xp + BK);   // x(1)
  float2 xB;
  __builtin_amdgcn_sched_barrier(0);
  #pragma unroll
  for (int s = 0; s < 2; ++s)
    #pragma unroll
    for (int i = 0; i < 2; ++i) {
      const int c = wid * 2 + i;
      __builtin_amdgcn_global_load_lds(
          (g_ushort*)(wf + (size_t)s * 8192 + c * 512 + lane * 8),
          (l_ushort*)&sm.g.B[s][c][0][0], 16, 0, 0);
    }
  __builtin_amdgcn_sched_barrier(0);
  *reinterpret_cast<unsigned*>(&sm.g.A[0][a_mfg][a_lane][a_q * 2]) = cvt2(x0);
  // retire gll(0) (+x(1), keeps gll(1) flying); A(0) visible after barrier
  asm volatile("s_waitcnt vmcnt(2) lgkmcnt(0)" ::: "memory");
  __builtin_amdgcn_sched_barrier(0);
  __builtin_amdgcn_s_barrier();
  __builtin_amdgcn_sched_barrier(0);

  // ---- main loop t = 0..61
  for (int t = 0; t < KSTEPS - 2; t += 2) {
    gstep(t,     xp, wf, wid, lane, a_mfg, a_lane, a_q, xA, xB, sm, acc);
    gstep(t + 1, xp, wf, wid, lane, a_mfg, a_lane, a_q, xB, xA, sm, acc);
  }

  // ---- t = 62 (no new issues): retire gll(62), compute, stage A(63)
  asm volatile("s_waitcnt vmcnt(3)" ::: "memory");   // keeps x(63)+gll(63)
  __builtin_amdgcn_sched_barrier(0);
  mfma4(sm, 62, wid, lane, acc);
  *reinterpret_cast<unsigned*>(&sm.g.A[1][a_mfg][a_lane][a_q * 2]) = cvt2(xA);
  asm volatile("s_waitcnt lgkmcnt(0)" ::: "memory");
  __builtin_amdgcn_sched_barrier(0);
  __builtin_amdgcn_s_barrier();
  __builtin_amdgcn_sched_barrier(0);

  // ---- t = 63: retire gll(63), compute
  asm volatile("s_waitcnt vmcnt(0)" ::: "memory");
  __builtin_amdgcn_sched_barrier(0);
  mfma4(sm, 63, wid, lane, acc);
  __syncthreads();   // full drain; safe to alias Sc over A/B

  // ---- epilogue: logits -> Sc (C/D layout: col=lane&15, row=(lane>>4)*4+r)
  #pragma unroll
  for (int mf = 0; mf < 2; ++mf)
    #pragma unroll
    for (int nf = 0; nf < 2; ++nf)
      #pragma unroll
      for (int r = 0; r < 4; ++r) {
        const int row = mf * 16 + ((lane >> 4) << 2) + r;
        const int col = wid * 32 + nf * 16 + (lane & 15);
        sm.Sc[row][col] = acc[mf][nf][r];
      }
  __syncthreads();

  // ---- routing: one wave per token, lane holds experts 4l..4l+3
  const float4 bsl = *reinterpret_cast<const float4*>(&bias[lane * 4]);
  const int g = lane >> 3;   // group of this lane's experts

  for (int m = wid; m < BM; m += 8) {
    float v[4];
    *reinterpret_cast<float4*>(v) =
        *reinterpret_cast<const float4*>(&sm.Sc[m][lane * 4]);

    // softmax (match jax: subtract row max, exp, divide by sum)
    float mx = fmaxf(fmaxf(v[0], v[1]), fmaxf(v[2], v[3]));
    #pragma unroll
    for (int s = 1; s < 64; s <<= 1) mx = fmaxf(mx, __shfl_xor(mx, s));
    float ex[4], sum = 0.f;
    #pragma unroll
    for (int j = 0; j < 4; ++j) { ex[j] = expf(v[j] - mx); sum += ex[j]; }
    #pragma unroll
    for (int s = 1; s < 64; s <<= 1) sum += __shfl_xor(sum, s);
    float sc[4], sel[4];
    sc[0] = ex[0] / sum; sc[1] = ex[1] / sum;
    sc[2] = ex[2] / sum; sc[3] = ex[3] / sum;
    sel[0] = sc[0] + bsl.x; sel[1] = sc[1] + bsl.y;
    sel[2] = sc[2] + bsl.z; sel[3] = sc[3] + bsl.w;

    // keep original scores for the gather
    *reinterpret_cast<float4*>(&sm.Sc[m][lane * 4]) =
        make_float4(sc[0], sc[1], sc[2], sc[3]);

    // group max (groups of 32 experts = 8 lanes)
    float gv = fmaxf(fmaxf(sel[0], sel[1]), fmaxf(sel[2], sel[3]));
    gv = fmaxf(gv, __shfl_xor(gv, 1));
    gv = fmaxf(gv, __shfl_xor(gv, 2));
    gv = fmaxf(gv, __shfl_xor(gv, 4));

    // top-4 groups, tie -> lower group index (jax.lax.top_k stability)
    unsigned gmask = 0;
    float gcur = gv;
    #pragma unroll
    for (int it = 0; it < NLIM; ++it) {
      float bv2 = gcur; int bi = g;
      #pragma unroll
      for (int s = 1; s < 64; s <<= 1) {
        float ov = __shfl_xor(bv2, s);
        int   oi = __shfl_xor(bi, s);
        if (ov > bv2 || (ov == bv2 && oi < bi)) { bv2 = ov; bi = oi; }
      }
      gmask |= 1u << bi;
      if (g == bi) gcur = -INFINITY;
    }
    if (!((gmask >> g) & 1u)) {
      sel[0] = sel[1] = sel[2] = sel[3] = -INFINITY;
    }

    // top-8 experts, tie -> lower expert index
    const int gtok = row0 + m;
    #pragma unroll
    for (int it = 0; it < TOPK; ++it) {
      float bv2 = sel[0]; int bi = lane * 4;
      #pragma unroll
      for (int j = 1; j < 4; ++j)
        if (sel[j] > bv2) { bv2 = sel[j]; bi = lane * 4 + j; }
      #pragma unroll
      for (int s = 1; s < 64; s <<= 1) {
        float ov = __shfl_xor(bv2, s);
        int   oi = __shfl_xor(bi, s);
        if (ov > bv2 || (ov == bv2 && oi < bi)) { bv2 = ov; bi = oi; }
      }
      if (lane == 0) {
        out_w[(size_t)gtok * TOPK + it]   = sm.Sc[m][bi] * 2.5f;
        out_idx[(size_t)gtok * TOPK + it] = (float)bi;
        atomicAdd(&hist[bi], 1);
      }
      if ((bi >> 2) == lane) sel[bi & 3] = -INFINITY;
    }
  }

  __syncthreads();
  for (int b = tid; b < NEXP; b += NTHREADS)
    if (hist[b]) atomicAdd(&out_load[b], (float)hist[b]);
}

extern "C" void kernel_launch(void* const* d_in, const int* in_sizes, int n_in,
                              void* d_out, int out_size, void* d_ws, size_t ws_size,
                              hipStream_t stream) {
  const float* x    = (const float*)d_in[0];
  const float* w    = (const float*)d_in[1];
  const float* bias = (const float*)d_in[2];
  float* out_w    = (float*)d_out;
  float* out_idx  = out_w + (size_t)T_TOKENS * TOPK;
  float* out_load = out_idx + (size_t)T_TOKENS * TOPK;
  unsigned short* wfrag = (unsigned short*)d_ws;   // 1 MB fragment-ordered fp16 w

  hipMemsetAsync(out_load, 0, NEXP * sizeof(float), stream);
  prep_w<<<256, 256, 0, stream>>>(w, wfrag);
  gate_kernel<<<T_TOKENS / BM, NTHREADS, 0, stream>>>(
      x, wfrag, bias, out_w, out_idx, out_load);
}